// Round 9
// baseline (226.064 us; speedup 1.0000x reference)
//
#include <hip/hip_runtime.h>
#include <stdint.h>

#define B_   4
#define C_   256
#define HW_  16384
#define P_   2048
#define THR_ 0.8f
#define INV_ 0.9999950000374997f

// ncand padded: counter b lives at ncand[b*16] (64 B apart -> no cacheline sharing)
#define NCIDX(b) ((b) << 4)

// ---------------- workspace layout (bytes) ----------------
#define OFF_NCAND 0
#define OFF_CAND  256                       // u64 cand[4][HW_]   512 KB
#define OFF_TOPK  524544                    // int topk[4][P_]     32 KB
#define OFF_POS   557312                    // int pos[4][HW_]    256 KB
#define OFF_G     819456                    // f32 r[4][C_][P_]     8 MB (GEMM2 out)
#define OFF_GT    9208064                   // bf16 gT[4][C_][P_]   4 MB  == [1024][2048]
#define OFF_Z2    13402368                  // bf16 z2[4][P_][C_]   4 MB  == [8192][256]
#define OFF_WADJB 17596672                  // bf16 Wadj[2048][2048] 8 MB
#define OFF_WGB   25985280                  // bf16 Wg[256][256]  128 KB
#define OFF_R     OFF_G
#define OFF_RANK  OFF_Z2                    // int rank[4][HW_] 256 KB, aliases z2 (dead before gemm1)

typedef __attribute__((ext_vector_type(8))) short bf16x8;
typedef __attribute__((ext_vector_type(4))) float f32x4;

__device__ __forceinline__ ushort f2bf(float f) {
    union { float f; unsigned u; } a; a.f = f;
    unsigned r = (a.u + 0x7fffu + ((a.u >> 16) & 1u)) >> 16;   // RNE
    return (ushort)r;
}
__device__ __forceinline__ float bf2f(ushort u) {
    union { unsigned u; float f; } a; a.u = (unsigned)u << 16;
    return a.f;
}

// Fused prep: convert Wadj (4096 blocks) + convert Wg (64 blocks) + zero pos/rank/ncand (128 blocks)
#define PREP_WADJ_BLOCKS 4096               // P_*P_/4/256
#define PREP_WG_BLOCKS   64                 // C_*C_/4/256
#define PREP_ZERO_BLOCKS 128                // (B_*HW_/4)*2 / 256
#define PREP_GRID (PREP_WADJ_BLOCKS + PREP_WG_BLOCKS + PREP_ZERO_BLOCKS)

__global__ __launch_bounds__(256) void prep_kernel(const float* __restrict__ Wadj,
                                                   ushort* __restrict__ WadjB,
                                                   const float* __restrict__ Wg,
                                                   ushort* __restrict__ WgB,
                                                   int* __restrict__ pos,
                                                   int* __restrict__ rankbuf,
                                                   int* __restrict__ ncand) {
    int bid = blockIdx.x;
    if (bid < PREP_WADJ_BLOCKS) {
        int i = bid * 256 + threadIdx.x;
        float4 v = ((const float4*)Wadj)[i];
        ushort4 o; o.x = f2bf(v.x); o.y = f2bf(v.y); o.z = f2bf(v.z); o.w = f2bf(v.w);
        ((ushort4*)WadjB)[i] = o;
    } else if (bid < PREP_WADJ_BLOCKS + PREP_WG_BLOCKS) {
        int i = (bid - PREP_WADJ_BLOCKS) * 256 + threadIdx.x;
        float4 v = ((const float4*)Wg)[i];
        ushort4 o; o.x = f2bf(v.x); o.y = f2bf(v.y); o.z = f2bf(v.z); o.w = f2bf(v.w);
        ((ushort4*)WgB)[i] = o;
    } else {
        int zb = bid - PREP_WADJ_BLOCKS - PREP_WG_BLOCKS;
        int i = zb * 256 + threadIdx.x;                // 0 .. 32767 (int4 units)
        int4 z = {0, 0, 0, 0};
        if (i < B_ * HW_ / 4) ((int4*)pos)[i] = z;
        else                  ((int4*)rankbuf)[i - B_ * HW_ / 4] = z;
        if (zb == 0 && threadIdx.x < 64) ncand[threadIdx.x] = 0;   // covers all padded slots
    }
}

// Block-aggregated compact: ballot+popcount per wave, LDS prefix across 4 waves,
// ONE global atomicAdd per block (256 total, padded counters). R6: -11.5us vs
// per-lane atomics on one shared cacheline.
__global__ __launch_bounds__(256) void compact_kernel(const float* __restrict__ edge,
                                                      unsigned long long* __restrict__ cand,
                                                      int* __restrict__ ncand) {
    int b = blockIdx.x >> 6;
    int i = (blockIdx.x & 63) * 256 + threadIdx.x;
    float e = edge[b * HW_ + i];
    bool act = (e >= THR_);
    unsigned long long mask = __ballot(act);
    int lane = threadIdx.x & 63;
    int wid  = threadIdx.x >> 6;
    int before = __popcll(mask & ((1ull << lane) - 1ull));
    __shared__ int wcnt[4];
    __shared__ int base;
    if (lane == 0) wcnt[wid] = __popcll(mask);
    __syncthreads();
    if (threadIdx.x == 0) {
        int c0 = wcnt[0], c1 = wcnt[1], c2 = wcnt[2], c3 = wcnt[3];
        wcnt[0] = 0; wcnt[1] = c0; wcnt[2] = c0 + c1; wcnt[3] = c0 + c1 + c2;
        base = atomicAdd(&ncand[NCIDX(b)], c0 + c1 + c2 + c3);
    }
    __syncthreads();
    if (act) {
        int slot = base + wcnt[wid] + before;
        unsigned vb = __float_as_uint(e);
        cand[(size_t)b * HW_ + slot] =
            ((unsigned long long)vb << 32) | (unsigned long long)(0xFFFFFFFFu - (unsigned)i);
    }
}

// 2-D partial rank: block (jb, tb, b) counts, for each candidate j in jb-tile,
// how many candidates in tb-tile compare greater. atomicAdd into rankbuf[j].
// NOTE R4 lesson: 2x2 super-tiling regressed — empty-block dispatch is nearly
// free; work concentration isn't.
__global__ __launch_bounds__(256) void rank_partial_kernel(
        const unsigned long long* __restrict__ cand,
        const int* __restrict__ ncand,
        int* __restrict__ rankbuf) {
    int b = blockIdx.z;
    int n = ncand[NCIDX(b)];
    int jb = blockIdx.x * 256, tb = blockIdx.y * 256;
    if (jb >= n || tb >= n) return;
    const unsigned long long* cb = cand + (size_t)b * HW_;
    __shared__ unsigned long long tile[256];
    int j = jb + threadIdx.x;
    unsigned long long kj = (j < n) ? cb[j] : 0ull;
    tile[threadIdx.x] = (tb + (int)threadIdx.x < n) ? cb[tb + threadIdx.x] : 0ull;
    __syncthreads();
    int cnt = 0;
#pragma unroll 16
    for (int k = 0; k < 256; ++k) cnt += (tile[k] > kj) ? 1 : 0;   // padded zeros never count
    if (j < n && cnt) atomicAdd(&rankbuf[b * HW_ + j], cnt);
}

// rank < P -> topk[rank]=idx, pos[idx]=rank+1.  Fallback (n < P) folded in.
__global__ __launch_bounds__(256) void rank_finalize_kernel(
        const unsigned long long* __restrict__ cand,
        const int* __restrict__ ncand,
        const int* __restrict__ rankbuf,
        int* __restrict__ topk,
        int* __restrict__ pos,
        const float* __restrict__ edge) {
    int b = blockIdx.y;
    int n = ncand[NCIDX(b)];
    int j = blockIdx.x * 256 + threadIdx.x;
    if (j < n) {
        int rank = rankbuf[b * HW_ + j];
        if (rank < P_) {
            int idx = (int)(0xFFFFFFFFu - (unsigned)(cand[(size_t)b * HW_ + j] & 0xFFFFFFFFull));
            topk[b * P_ + rank] = idx;
            pos[b * HW_ + idx] = rank + 1;
        }
    }
    if (n < P_ && blockIdx.x == 0 && threadIdx.x == 0) {
        int cnt = n;
        for (int i = 0; i < HW_ && cnt < P_; ++i) {
            if (edge[b * HW_ + i] < THR_) {
                topk[b * P_ + cnt] = i;
                pos[b * HW_ + i] = cnt + 1;
                cnt++;
            }
        }
    }
}

// index-driven gather: one block per (b,c) row; stage x-row in LDS (coalesced),
// gather topk positions from LDS, write gT row fully coalesced (16B/thread runs).
__global__ __launch_bounds__(256) void gather_lds_kernel(const float* __restrict__ x,
                                                         const int* __restrict__ topk,
                                                         ushort* __restrict__ gT) {
    __shared__ float row[HW_];              // 64 KB -> 2 blocks/CU
    int bc = blockIdx.x;                    // b*C_ + c
    int b = bc >> 8;
    const float* xr = x + (size_t)bc * HW_;
#pragma unroll
    for (int i = 0; i < 16; ++i)
        ((float4*)row)[threadIdx.x + i * 256] = ((const float4*)xr)[threadIdx.x + i * 256];
    __syncthreads();
    const int* tk = topk + b * P_;
    int p0 = threadIdx.x * 8;
    int4 i0 = *(const int4*)&tk[p0];
    int4 i1 = *(const int4*)&tk[p0 + 4];
    ushort4 o0, o1;
    o0.x = f2bf(row[i0.x]); o0.y = f2bf(row[i0.y]); o0.z = f2bf(row[i0.z]); o0.w = f2bf(row[i0.w]);
    o1.x = f2bf(row[i1.x]); o1.y = f2bf(row[i1.y]); o1.z = f2bf(row[i1.z]); o1.w = f2bf(row[i1.w]);
    ushort* gp = gT + (size_t)bc * P_ + p0;
    *(ushort4*)gp = o0;
    *(ushort4*)(gp + 4) = o1;
}

#define MFMA16(AB, BB)                                                              \
    _Pragma("unroll")                                                               \
    for (int i = 0; i < 4; ++i)                                                     \
    _Pragma("unroll")                                                               \
        for (int j = 0; j < 4; ++j)                                                 \
            acc[i][j] = __builtin_amdgcn_mfma_f32_16x16x32_bf16(                    \
                __builtin_bit_cast(bf16x8, AB[i]),                                  \
                __builtin_bit_cast(bf16x8, BB[j]), acc[i][j], 0, 0, 0);

// ============ GEMM1: 128x128 LDS-tiled 4-wave block (R9 rewrite) ============
// M=2048 (o), N=1024 (b*256+c), K=2048. Grid 16x8 = 128 blocks, 4 waves (2x2
// of 64x64). BK=32, double-buffered LDS, padded row stride 40 elems (80 B):
// read banks (20r+4q) mod 32 -> 2-way max (free, m136); all uint4 LDS accesses
// 16B-aligned (80 % 16 == 0). Reg-staged with T14 split: global loads for tile
// t+1 issue BEFORE tile t's MFMAs, ds_write after. A read 8x (64 MB) + B read
// 16x (64 MB) = 128 MB cache traffic vs 268 MB for the per-wave version.
// Epilogue identical to the proven MODE 1 path via mt_eff/nt_eff.
#define G1_LDK 40
__global__ __launch_bounds__(256) void gemm1_lds_kernel(
        const ushort* __restrict__ A, const ushort* __restrict__ B,
        const float* __restrict__ gamma, const float* __restrict__ beta,
        const ushort* __restrict__ residT, ushort* __restrict__ out) {
    __shared__ ushort Asm[2][128][G1_LDK];
    __shared__ ushort Bsm[2][128][G1_LDK];
    const int mtb = blockIdx.x >> 3;         // 0..15
    const int ntb = blockIdx.x & 7;          // 0..7
    const int w   = threadIdx.x >> 6;        // wave 0..3
    const int wr  = w >> 1, wc = w & 1;
    const int lane = threadIdx.x & 63;
    const int quad = lane >> 4, ln = lane & 15;
    const int srow = lane >> 2;              // 0..15 (staging row within 16-row group)
    const int sslot = lane & 3;              // 0..3  (16B granule within 64B row)

    // staging global base: wave w stages rows [w*32, w*32+32) of each 128-row panel,
    // in two 16-row instructions (m = 0,1).
    const ushort* gpa = A + (size_t)(mtb * 128 + w * 32 + srow) * 2048 + sslot * 8;
    const ushort* gpb = B + (size_t)(ntb * 128 + w * 32 + srow) * 2048 + sslot * 8;

    f32x4 acc[4][4];
#pragma unroll
    for (int i = 0; i < 4; ++i)
#pragma unroll
        for (int j = 0; j < 4; ++j) acc[i][j] = (f32x4){0.f, 0.f, 0.f, 0.f};

    uint4 ga[2], gb[2];
#pragma unroll
    for (int m = 0; m < 2; ++m) {
        ga[m] = *(const uint4*)(gpa + (size_t)m * 16 * 2048);
        gb[m] = *(const uint4*)(gpb + (size_t)m * 16 * 2048);
    }
#pragma unroll
    for (int m = 0; m < 2; ++m) {
        *(uint4*)&Asm[0][w * 32 + m * 16 + srow][sslot * 8] = ga[m];
        *(uint4*)&Bsm[0][w * 32 + m * 16 + srow][sslot * 8] = gb[m];
    }
    __syncthreads();

    for (int t = 0; t < 64; ++t) {
        const int cur = t & 1;
        if (t < 63) {
            const int ko = (t + 1) * 32;
#pragma unroll
            for (int m = 0; m < 2; ++m) {
                ga[m] = *(const uint4*)(gpa + (size_t)m * 16 * 2048 + ko);
                gb[m] = *(const uint4*)(gpb + (size_t)m * 16 * 2048 + ko);
            }
        }
        {
            uint4 av[4], bv[4];
#pragma unroll
            for (int i = 0; i < 4; ++i) {
                av[i] = *(const uint4*)&Asm[cur][wr * 64 + i * 16 + ln][quad * 8];
                bv[i] = *(const uint4*)&Bsm[cur][wc * 64 + i * 16 + ln][quad * 8];
            }
            MFMA16(av, bv)
        }
        if (t < 63) {
#pragma unroll
            for (int m = 0; m < 2; ++m) {
                *(uint4*)&Asm[cur ^ 1][w * 32 + m * 16 + srow][sslot * 8] = ga[m];
                *(uint4*)&Bsm[cur ^ 1][w * 32 + m * 16 + srow][sslot * 8] = gb[m];
            }
        }
        __syncthreads();
    }

    const int mte = mtb * 2 + wr;
    const int nte = ntb * 2 + wc;
    float gm[16], bt[16];
#pragma unroll
    for (int i = 0; i < 4; ++i)
#pragma unroll
        for (int rg = 0; rg < 4; ++rg) {
            int row = mte * 64 + i * 16 + quad * 4 + rg;
            gm[i * 4 + rg] = gamma[row] * INV_;
            bt[i * 4 + rg] = beta[row];
        }
#pragma unroll
    for (int j = 0; j < 4; ++j) {
        int n = nte * 64 + j * 16 + ln;
        int bb = n >> 8;
        int cc = n & (C_ - 1);
        const ushort* gr = residT + (size_t)n * P_;           // gT row (b,c), indexed by o
        ushort* op = out + (size_t)bb * P_ * C_ + cc;
#pragma unroll
        for (int i = 0; i < 4; ++i) {
            int rbase = mte * 64 + i * 16 + quad * 4;
            ushort4 rv = *(const ushort4*)&gr[rbase];
            float rf[4] = {bf2f(rv.x), bf2f(rv.y), bf2f(rv.z), bf2f(rv.w)};
#pragma unroll
            for (int rg = 0; rg < 4; ++rg) {
                float v = fmaxf(acc[i][j][rg] * gm[i * 4 + rg] + bt[i * 4 + rg], 0.f) + rf[rg];
                op[(size_t)(rbase + rg) * C_] = f2bf(v);
            }
        }
    }
}

// ------------- per-wave NT MFMA GEMM (gemm2 only now), 4-deep ring -------------
// MODE 2 (gemm2): M=256 (d), N=8192 (b*2048+p), K=256
template<int MODE, int KDIM, int NTN, int WPB>
__global__ __launch_bounds__(64 * WPB) void gemm_wave_kernel(
        const ushort* __restrict__ A, const ushort* __restrict__ B,
        const float* __restrict__ gamma, const float* __restrict__ beta,
        const ushort* __restrict__ residT, void* __restrict__ out) {
    constexpr int KSTEPS = KDIM / 32;        // 32-k chunks; KSTEPS is a multiple of 4
    const int bid = blockIdx.x;
    const int wid = threadIdx.x >> 6;        // wave within block (0..WPB-1)
    const int mt = (bid / NTN) * WPB + wid;
    const int nt = bid % NTN;
    const int lane = threadIdx.x & 63;       // 0..63
    const int quad = lane >> 4, ln = lane & 15;

    const ushort* pa[4];
    const ushort* pb[4];
#pragma unroll
    for (int i = 0; i < 4; ++i) {
        pa[i] = A + (size_t)(mt * 64 + i * 16 + ln) * KDIM + quad * 8;
        pb[i] = B + (size_t)(nt * 64 + i * 16 + ln) * KDIM + quad * 8;
    }

    f32x4 acc[4][4];
#pragma unroll
    for (int i = 0; i < 4; ++i)
#pragma unroll
        for (int j = 0; j < 4; ++j) acc[i][j] = (f32x4){0.f, 0.f, 0.f, 0.f};

    uint4 A4[4][4], B4[4][4];
#pragma unroll
    for (int t = 0; t < 4; ++t)
#pragma unroll
        for (int i = 0; i < 4; ++i) {
            A4[t][i] = *(const uint4*)(pa[i] + t * 32);
            B4[t][i] = *(const uint4*)(pb[i] + t * 32);
        }

    int koff = 4 * 32;
    for (int s = 0; s < KSTEPS - 4; s += 4) {
#pragma unroll
        for (int t = 0; t < 4; ++t) {
            MFMA16(A4[t], B4[t])
#pragma unroll
            for (int i = 0; i < 4; ++i) {
                A4[t][i] = *(const uint4*)(pa[i] + koff + t * 32);
                B4[t][i] = *(const uint4*)(pb[i] + koff + t * 32);
            }
        }
        koff += 128;
    }
#pragma unroll
    for (int t = 0; t < 4; ++t) {
        MFMA16(A4[t], B4[t])
    }

    float gm[16], bt[16];
#pragma unroll
    for (int i = 0; i < 4; ++i)
#pragma unroll
        for (int rg = 0; rg < 4; ++rg) {
            int row = mt * 64 + i * 16 + quad * 4 + rg;
            gm[i * 4 + rg] = gamma[row] * INV_;
            bt[i * 4 + rg] = beta[row];
        }

    if (MODE == 1) {
#pragma unroll
        for (int j = 0; j < 4; ++j) {
            int n = nt * 64 + j * 16 + ln;
            int bb = n >> 8;
            int cc = n & (C_ - 1);
            const ushort* gr = residT + (size_t)n * P_;
            ushort* op = (ushort*)out + (size_t)bb * P_ * C_ + cc;
#pragma unroll
            for (int i = 0; i < 4; ++i) {
                int rbase = mt * 64 + i * 16 + quad * 4;
                ushort4 rv = *(const ushort4*)&gr[rbase];
                float rf[4] = {bf2f(rv.x), bf2f(rv.y), bf2f(rv.z), bf2f(rv.w)};
#pragma unroll
                for (int rg = 0; rg < 4; ++rg) {
                    int row = rbase + rg;
                    float v = fmaxf(acc[i][j][rg] * gm[i * 4 + rg] + bt[i * 4 + rg], 0.f) + rf[rg];
                    op[(size_t)row * C_] = f2bf(v);
                }
            }
        }
    } else {
#pragma unroll
        for (int j = 0; j < 4; ++j) {
            int n = nt * 64 + j * 16 + ln;
            int bb = n >> 11;
            int pp = n & (P_ - 1);
            float* op = (float*)out + (size_t)bb * C_ * P_ + pp;
#pragma unroll
            for (int i = 0; i < 4; ++i)
#pragma unroll
                for (int rg = 0; rg < 4; ++rg) {
                    int row = mt * 64 + i * 16 + quad * 4 + rg;
                    op[(size_t)row * P_] =
                        fmaxf(acc[i][j][rg] * gm[i * 4 + rg] + bt[i * 4 + rg], 0.f);
                }
        }
    }
}

// out[b][d][hw] = pos ? r[b][d][pos-1] : x[b][d][hw]
__global__ __launch_bounds__(256) void output_kernel(const float* __restrict__ x,
                                                     const int* __restrict__ pos,
                                                     const float* __restrict__ r,
                                                     float* __restrict__ out) {
    size_t v = (size_t)blockIdx.x * 256 + threadIdx.x;
    size_t e0 = v * 4;
    int hw = (int)(e0 & (HW_ - 1));
    int bc = (int)(e0 >> 14);
    int d = bc & (C_ - 1);
    int b = bc >> 8;
    float4 xv = *(const float4*)&x[e0];
    int4 pv = *(const int4*)&pos[b * HW_ + hw];
    const float* rrow = r + ((size_t)b * C_ + d) * P_;
    float4 ov = xv;
    if (pv.x) ov.x = rrow[pv.x - 1];
    if (pv.y) ov.y = rrow[pv.y - 1];
    if (pv.z) ov.z = rrow[pv.z - 1];
    if (pv.w) ov.w = rrow[pv.w - 1];
    *(float4*)&out[e0] = ov;
}

extern "C" void kernel_launch(void* const* d_in, const int* in_sizes, int n_in,
                              void* d_out, int out_size, void* d_ws, size_t ws_size,
                              hipStream_t stream) {
    const float* x    = (const float*)d_in[0];
    const float* edge = (const float*)d_in[1];
    const float* Wadj = (const float*)d_in[2];
    const float* ga   = (const float*)d_in[3];
    const float* be   = (const float*)d_in[4];
    const float* Wg   = (const float*)d_in[5];
    const float* gw   = (const float*)d_in[6];
    const float* bw   = (const float*)d_in[7];
    float* out = (float*)d_out;

    char* ws = (char*)d_ws;
    int*                ncand = (int*)(ws + OFF_NCAND);
    unsigned long long* cand  = (unsigned long long*)(ws + OFF_CAND);
    int*                topk  = (int*)(ws + OFF_TOPK);
    int*                pos   = (int*)(ws + OFF_POS);
    int*                rankb = (int*)(ws + OFF_RANK);
    ushort*             gT    = (ushort*)(ws + OFF_GT);
    ushort*             z2    = (ushort*)(ws + OFF_Z2);
    ushort*             WadjB = (ushort*)(ws + OFF_WADJB);
    ushort*             WgB   = (ushort*)(ws + OFF_WGB);
    float*              rbuf  = (float*)(ws + OFF_R);

    prep_kernel<<<PREP_GRID, 256, 0, stream>>>(Wadj, WadjB, Wg, WgB, pos, rankb, ncand);
    compact_kernel<<<B_ * 64, 256, 0, stream>>>(edge, cand, ncand);
    {
        dim3 grid(64, 64, B_);
        rank_partial_kernel<<<grid, 256, 0, stream>>>(cand, ncand, rankb);
    }
    {
        dim3 grid(64, B_);
        rank_finalize_kernel<<<grid, 64 * 4, 0, stream>>>(cand, ncand, rankb, topk, pos, edge);
    }
    gather_lds_kernel<<<B_ * C_, 256, 0, stream>>>(x, topk, gT);

    // GEMM1: 128x128 LDS-tiled blocks -> 16x8 = 128 blocks x 4 waves
    gemm1_lds_kernel<<<128, 256, 0, stream>>>(WadjB, gT, ga, be, gT, z2);
    // GEMM2: M=256, N=8192 (b,p), K=256 -> 4x128 wave tiles = 512 waves
    gemm_wave_kernel<2, 256, 128, 1><<<512, 64, 0, stream>>>(WgB, z2, gw, bw, nullptr, rbuf);

    output_kernel<<<(B_ * C_ * HW_) / 4 / 256, 256, 0, stream>>>(x, pos, rbuf, out);
}

// Round 10
// 218.697 us; speedup vs baseline: 1.0337x; 1.0337x over previous
//
#include <hip/hip_runtime.h>
#include <stdint.h>

#define B_   4
#define C_   256
#define HW_  16384
#define P_   2048
#define THR_ 0.8f
#define INV_ 0.9999950000374997f

// ncand padded: counter b lives at ncand[b*16] (64 B apart -> no cacheline sharing)
#define NCIDX(b) ((b) << 4)

// ---------------- workspace layout (bytes) ----------------
#define OFF_NCAND 0
#define OFF_CAND  256                       // u64 cand[4][HW_]   512 KB
#define OFF_TOPK  524544                    // int topk[4][P_]     32 KB
#define OFF_POS   557312                    // int pos[4][HW_]    256 KB
#define OFF_G     819456                    // f32 r[4][C_][P_]     8 MB (GEMM2 out)
#define OFF_GT    9208064                   // bf16 gT[4][C_][P_]   4 MB  == [1024][2048]
#define OFF_Z2    13402368                  // bf16 z2[4][P_][C_]   4 MB  == [8192][256]
#define OFF_WADJB 17596672                  // bf16 Wadj[2048][2048] 8 MB
#define OFF_WGB   25985280                  // bf16 Wg[256][256]  128 KB
#define OFF_R     OFF_G
#define OFF_RANK  OFF_Z2                    // int rank[4][HW_] 256 KB, aliases z2 (dead before gemm1)

typedef __attribute__((ext_vector_type(8))) short bf16x8;
typedef __attribute__((ext_vector_type(4))) float f32x4;

__device__ __forceinline__ ushort f2bf(float f) {
    union { float f; unsigned u; } a; a.f = f;
    unsigned r = (a.u + 0x7fffu + ((a.u >> 16) & 1u)) >> 16;   // RNE
    return (ushort)r;
}
__device__ __forceinline__ float bf2f(ushort u) {
    union { unsigned u; float f; } a; a.u = (unsigned)u << 16;
    return a.f;
}

// Fused prep: convert Wadj (4096 blocks) + convert Wg (64 blocks) + zero pos/rank/ncand (128 blocks)
#define PREP_WADJ_BLOCKS 4096               // P_*P_/4/256
#define PREP_WG_BLOCKS   64                 // C_*C_/4/256
#define PREP_ZERO_BLOCKS 128                // (B_*HW_/4)*2 / 256
#define PREP_GRID (PREP_WADJ_BLOCKS + PREP_WG_BLOCKS + PREP_ZERO_BLOCKS)

__global__ __launch_bounds__(256) void prep_kernel(const float* __restrict__ Wadj,
                                                   ushort* __restrict__ WadjB,
                                                   const float* __restrict__ Wg,
                                                   ushort* __restrict__ WgB,
                                                   int* __restrict__ pos,
                                                   int* __restrict__ rankbuf,
                                                   int* __restrict__ ncand) {
    int bid = blockIdx.x;
    if (bid < PREP_WADJ_BLOCKS) {
        int i = bid * 256 + threadIdx.x;
        float4 v = ((const float4*)Wadj)[i];
        ushort4 o; o.x = f2bf(v.x); o.y = f2bf(v.y); o.z = f2bf(v.z); o.w = f2bf(v.w);
        ((ushort4*)WadjB)[i] = o;
    } else if (bid < PREP_WADJ_BLOCKS + PREP_WG_BLOCKS) {
        int i = (bid - PREP_WADJ_BLOCKS) * 256 + threadIdx.x;
        float4 v = ((const float4*)Wg)[i];
        ushort4 o; o.x = f2bf(v.x); o.y = f2bf(v.y); o.z = f2bf(v.z); o.w = f2bf(v.w);
        ((ushort4*)WgB)[i] = o;
    } else {
        int zb = bid - PREP_WADJ_BLOCKS - PREP_WG_BLOCKS;
        int i = zb * 256 + threadIdx.x;                // 0 .. 32767 (int4 units)
        int4 z = {0, 0, 0, 0};
        if (i < B_ * HW_ / 4) ((int4*)pos)[i] = z;
        else                  ((int4*)rankbuf)[i - B_ * HW_ / 4] = z;
        if (zb == 0 && threadIdx.x < 64) ncand[threadIdx.x] = 0;   // covers all padded slots
    }
}

// Block-aggregated compact: ballot+popcount per wave, LDS prefix across 4 waves,
// ONE global atomicAdd per block (256 total, padded counters). R6: -11.5us.
__global__ __launch_bounds__(256) void compact_kernel(const float* __restrict__ edge,
                                                      unsigned long long* __restrict__ cand,
                                                      int* __restrict__ ncand) {
    int b = blockIdx.x >> 6;
    int i = (blockIdx.x & 63) * 256 + threadIdx.x;
    float e = edge[b * HW_ + i];
    bool act = (e >= THR_);
    unsigned long long mask = __ballot(act);
    int lane = threadIdx.x & 63;
    int wid  = threadIdx.x >> 6;
    int before = __popcll(mask & ((1ull << lane) - 1ull));
    __shared__ int wcnt[4];
    __shared__ int base;
    if (lane == 0) wcnt[wid] = __popcll(mask);
    __syncthreads();
    if (threadIdx.x == 0) {
        int c0 = wcnt[0], c1 = wcnt[1], c2 = wcnt[2], c3 = wcnt[3];
        wcnt[0] = 0; wcnt[1] = c0; wcnt[2] = c0 + c1; wcnt[3] = c0 + c1 + c2;
        base = atomicAdd(&ncand[NCIDX(b)], c0 + c1 + c2 + c3);
    }
    __syncthreads();
    if (act) {
        int slot = base + wcnt[wid] + before;
        unsigned vb = __float_as_uint(e);
        cand[(size_t)b * HW_ + slot] =
            ((unsigned long long)vb << 32) | (unsigned long long)(0xFFFFFFFFu - (unsigned)i);
    }
}

// 2-D partial rank: block (jb, tb, b) counts, for each candidate j in jb-tile,
// how many candidates in tb-tile compare greater. atomicAdd into rankbuf[j].
// NOTE R4 lesson: super-tiling regressed; empty-block dispatch is nearly free.
__global__ __launch_bounds__(256) void rank_partial_kernel(
        const unsigned long long* __restrict__ cand,
        const int* __restrict__ ncand,
        int* __restrict__ rankbuf) {
    int b = blockIdx.z;
    int n = ncand[NCIDX(b)];
    int jb = blockIdx.x * 256, tb = blockIdx.y * 256;
    if (jb >= n || tb >= n) return;
    const unsigned long long* cb = cand + (size_t)b * HW_;
    __shared__ unsigned long long tile[256];
    int j = jb + threadIdx.x;
    unsigned long long kj = (j < n) ? cb[j] : 0ull;
    tile[threadIdx.x] = (tb + (int)threadIdx.x < n) ? cb[tb + threadIdx.x] : 0ull;
    __syncthreads();
    int cnt = 0;
#pragma unroll 16
    for (int k = 0; k < 256; ++k) cnt += (tile[k] > kj) ? 1 : 0;   // padded zeros never count
    if (j < n && cnt) atomicAdd(&rankbuf[b * HW_ + j], cnt);
}

// rank < P -> topk[rank]=idx, pos[idx]=rank+1.  Fallback (n < P) folded in.
__global__ __launch_bounds__(256) void rank_finalize_kernel(
        const unsigned long long* __restrict__ cand,
        const int* __restrict__ ncand,
        const int* __restrict__ rankbuf,
        int* __restrict__ topk,
        int* __restrict__ pos,
        const float* __restrict__ edge) {
    int b = blockIdx.y;
    int n = ncand[NCIDX(b)];
    int j = blockIdx.x * 256 + threadIdx.x;
    if (j < n) {
        int rank = rankbuf[b * HW_ + j];
        if (rank < P_) {
            int idx = (int)(0xFFFFFFFFu - (unsigned)(cand[(size_t)b * HW_ + j] & 0xFFFFFFFFull));
            topk[b * P_ + rank] = idx;
            pos[b * HW_ + idx] = rank + 1;
        }
    }
    if (n < P_ && blockIdx.x == 0 && threadIdx.x == 0) {
        int cnt = n;
        for (int i = 0; i < HW_ && cnt < P_; ++i) {
            if (edge[b * HW_ + i] < THR_) {
                topk[b * P_ + cnt] = i;
                pos[b * HW_ + i] = cnt + 1;
                cnt++;
            }
        }
    }
}

// index-driven gather: one block per (b,c) row; stage x-row in LDS (coalesced),
// gather topk positions from LDS, write gT row fully coalesced (16B/thread runs).
__global__ __launch_bounds__(256) void gather_lds_kernel(const float* __restrict__ x,
                                                         const int* __restrict__ topk,
                                                         ushort* __restrict__ gT) {
    __shared__ float row[HW_];              // 64 KB -> 2 blocks/CU
    int bc = blockIdx.x;                    // b*C_ + c
    int b = bc >> 8;
    const float* xr = x + (size_t)bc * HW_;
#pragma unroll
    for (int i = 0; i < 16; ++i)
        ((float4*)row)[threadIdx.x + i * 256] = ((const float4*)xr)[threadIdx.x + i * 256];
    __syncthreads();
    const int* tk = topk + b * P_;
    int p0 = threadIdx.x * 8;
    int4 i0 = *(const int4*)&tk[p0];
    int4 i1 = *(const int4*)&tk[p0 + 4];
    ushort4 o0, o1;
    o0.x = f2bf(row[i0.x]); o0.y = f2bf(row[i0.y]); o0.z = f2bf(row[i0.z]); o0.w = f2bf(row[i0.w]);
    o1.x = f2bf(row[i1.x]); o1.y = f2bf(row[i1.y]); o1.z = f2bf(row[i1.z]); o1.w = f2bf(row[i1.w]);
    ushort* gp = gT + (size_t)bc * P_ + p0;
    *(ushort4*)gp = o0;
    *(ushort4*)(gp + 4) = o1;
}

#define MFMA16(AB, BB)                                                              \
    _Pragma("unroll")                                                               \
    for (int i = 0; i < 4; ++i)                                                     \
    _Pragma("unroll")                                                               \
        for (int j = 0; j < 4; ++j)                                                 \
            acc[i][j] = __builtin_amdgcn_mfma_f32_16x16x32_bf16(                    \
                __builtin_bit_cast(bf16x8, AB[i]),                                  \
                __builtin_bit_cast(bf16x8, BB[j]), acc[i][j], 0, 0, 0);

// ============ GEMM1 v3: 64x128 LDS-tiled 4-wave blocks (R10) ============
// R9 counters: Occupancy 4.6% (128 blocks, half chip idle), MfmaUtil 7%,
// HBM 12.7% -> latency-bound, not BW. Fixes: (1) M-tile 128->64 => 32x8 = 256
// blocks, all CUs busy; (2) BK 32->64 => 32 iterations, half the barrier drains.
// 4 waves as 2x2 over 64x128 -> per-wave 32x64, acc[2][4]. LDS row stride 72
// ushorts (144 B): read/write 16B spans tile the 32 banks at 8 lanes/span ->
// throughput-conflict-free. Single barrier per iter (write buf^1 while reading
// buf). T14 split: next-tile global loads issue before the MFMA phase.
#define G1_LDK 72
__global__ __launch_bounds__(256) void gemm1_lds_kernel(
        const ushort* __restrict__ A, const ushort* __restrict__ B,
        const float* __restrict__ gamma, const float* __restrict__ beta,
        const ushort* __restrict__ residT, ushort* __restrict__ out) {
    __shared__ ushort Asm[2][64][G1_LDK];    // 18 KB
    __shared__ ushort Bsm[2][128][G1_LDK];   // 36 KB
    const int mtb = blockIdx.x >> 3;         // 0..31 (M tile of 64)
    const int ntb = blockIdx.x & 7;          // 0..7  (N tile of 128)
    const int w   = threadIdx.x >> 6;        // wave 0..3
    const int wr  = w >> 1, wc = w & 1;      // 2x2 -> per-wave 32x64
    const int lane = threadIdx.x & 63;
    const int quad = lane >> 4, ln = lane & 15;
    const int tid  = threadIdx.x;
    const int srow = tid >> 3;               // 0..31 (staging row base)
    const int sslot = tid & 7;               // 0..7  (16B granule in 128B row)

    // staging bases: A granules (srow, srow+32), B granules (srow + 32m, m=0..3)
    const ushort* gA = A + (size_t)(mtb * 64 + srow) * 2048 + sslot * 8;
    const ushort* gB = B + (size_t)(ntb * 128 + srow) * 2048 + sslot * 8;

    f32x4 acc[2][4];
#pragma unroll
    for (int i = 0; i < 2; ++i)
#pragma unroll
        for (int j = 0; j < 4; ++j) acc[i][j] = (f32x4){0.f, 0.f, 0.f, 0.f};

    uint4 ra[2], rb[4];
#pragma unroll
    for (int m = 0; m < 2; ++m) ra[m] = *(const uint4*)(gA + (size_t)m * 32 * 2048);
#pragma unroll
    for (int m = 0; m < 4; ++m) rb[m] = *(const uint4*)(gB + (size_t)m * 32 * 2048);
#pragma unroll
    for (int m = 0; m < 2; ++m) *(uint4*)&Asm[0][srow + m * 32][sslot * 8] = ra[m];
#pragma unroll
    for (int m = 0; m < 4; ++m) *(uint4*)&Bsm[0][srow + m * 32][sslot * 8] = rb[m];
    __syncthreads();

    for (int t = 0; t < 32; ++t) {
        const int cur = t & 1;
        if (t < 31) {
            const int ko = (t + 1) * 64;
#pragma unroll
            for (int m = 0; m < 2; ++m) ra[m] = *(const uint4*)(gA + (size_t)m * 32 * 2048 + ko);
#pragma unroll
            for (int m = 0; m < 4; ++m) rb[m] = *(const uint4*)(gB + (size_t)m * 32 * 2048 + ko);
        }
#pragma unroll
        for (int kk = 0; kk < 2; ++kk) {
            uint4 av[2], bv[4];
#pragma unroll
            for (int i = 0; i < 2; ++i)
                av[i] = *(const uint4*)&Asm[cur][wr * 32 + i * 16 + ln][kk * 32 + quad * 8];
#pragma unroll
            for (int j = 0; j < 4; ++j)
                bv[j] = *(const uint4*)&Bsm[cur][wc * 64 + j * 16 + ln][kk * 32 + quad * 8];
#pragma unroll
            for (int i = 0; i < 2; ++i)
#pragma unroll
                for (int j = 0; j < 4; ++j)
                    acc[i][j] = __builtin_amdgcn_mfma_f32_16x16x32_bf16(
                        __builtin_bit_cast(bf16x8, av[i]),
                        __builtin_bit_cast(bf16x8, bv[j]), acc[i][j], 0, 0, 0);
        }
        if (t < 31) {
#pragma unroll
            for (int m = 0; m < 2; ++m) *(uint4*)&Asm[cur ^ 1][srow + m * 32][sslot * 8] = ra[m];
#pragma unroll
            for (int m = 0; m < 4; ++m) *(uint4*)&Bsm[cur ^ 1][srow + m * 32][sslot * 8] = rb[m];
        }
        __syncthreads();
    }

    float gm[8], bt[8];
#pragma unroll
    for (int i = 0; i < 2; ++i)
#pragma unroll
        for (int rg = 0; rg < 4; ++rg) {
            int row = mtb * 64 + wr * 32 + i * 16 + quad * 4 + rg;
            gm[i * 4 + rg] = gamma[row] * INV_;
            bt[i * 4 + rg] = beta[row];
        }
#pragma unroll
    for (int j = 0; j < 4; ++j) {
        int n = ntb * 128 + wc * 64 + j * 16 + ln;
        int bb = n >> 8;
        int cc = n & (C_ - 1);
        const ushort* gr = residT + (size_t)n * P_;           // gT row (b,c), indexed by o
        ushort* op = out + (size_t)bb * P_ * C_ + cc;
#pragma unroll
        for (int i = 0; i < 2; ++i) {
            int rbase = mtb * 64 + wr * 32 + i * 16 + quad * 4;
            ushort4 rv = *(const ushort4*)&gr[rbase];
            float rf[4] = {bf2f(rv.x), bf2f(rv.y), bf2f(rv.z), bf2f(rv.w)};
#pragma unroll
            for (int rg = 0; rg < 4; ++rg) {
                float v = fmaxf(acc[i][j][rg] * gm[i * 4 + rg] + bt[i * 4 + rg], 0.f) + rf[rg];
                op[(size_t)(rbase + rg) * C_] = f2bf(v);
            }
        }
    }
}

// ------------- per-wave NT MFMA GEMM (gemm2 only), 4-deep ring -------------
// MODE 2 (gemm2): M=256 (d), N=8192 (b*2048+p), K=256
template<int MODE, int KDIM, int NTN, int WPB>
__global__ __launch_bounds__(64 * WPB) void gemm_wave_kernel(
        const ushort* __restrict__ A, const ushort* __restrict__ B,
        const float* __restrict__ gamma, const float* __restrict__ beta,
        const ushort* __restrict__ residT, void* __restrict__ out) {
    constexpr int KSTEPS = KDIM / 32;        // 32-k chunks; KSTEPS is a multiple of 4
    const int bid = blockIdx.x;
    const int wid = threadIdx.x >> 6;
    const int mt = (bid / NTN) * WPB + wid;
    const int nt = bid % NTN;
    const int lane = threadIdx.x & 63;
    const int quad = lane >> 4, ln = lane & 15;

    const ushort* pa[4];
    const ushort* pb[4];
#pragma unroll
    for (int i = 0; i < 4; ++i) {
        pa[i] = A + (size_t)(mt * 64 + i * 16 + ln) * KDIM + quad * 8;
        pb[i] = B + (size_t)(nt * 64 + i * 16 + ln) * KDIM + quad * 8;
    }

    f32x4 acc[4][4];
#pragma unroll
    for (int i = 0; i < 4; ++i)
#pragma unroll
        for (int j = 0; j < 4; ++j) acc[i][j] = (f32x4){0.f, 0.f, 0.f, 0.f};

    uint4 A4[4][4], B4[4][4];
#pragma unroll
    for (int t = 0; t < 4; ++t)
#pragma unroll
        for (int i = 0; i < 4; ++i) {
            A4[t][i] = *(const uint4*)(pa[i] + t * 32);
            B4[t][i] = *(const uint4*)(pb[i] + t * 32);
        }

    int koff = 4 * 32;
    for (int s = 0; s < KSTEPS - 4; s += 4) {
#pragma unroll
        for (int t = 0; t < 4; ++t) {
            MFMA16(A4[t], B4[t])
#pragma unroll
            for (int i = 0; i < 4; ++i) {
                A4[t][i] = *(const uint4*)(pa[i] + koff + t * 32);
                B4[t][i] = *(const uint4*)(pb[i] + koff + t * 32);
            }
        }
        koff += 128;
    }
#pragma unroll
    for (int t = 0; t < 4; ++t) {
        MFMA16(A4[t], B4[t])
    }

    float gm[16], bt[16];
#pragma unroll
    for (int i = 0; i < 4; ++i)
#pragma unroll
        for (int rg = 0; rg < 4; ++rg) {
            int row = mt * 64 + i * 16 + quad * 4 + rg;
            gm[i * 4 + rg] = gamma[row] * INV_;
            bt[i * 4 + rg] = beta[row];
        }

    if (MODE == 1) {
#pragma unroll
        for (int j = 0; j < 4; ++j) {
            int n = nt * 64 + j * 16 + ln;
            int bb = n >> 8;
            int cc = n & (C_ - 1);
            const ushort* gr = residT + (size_t)n * P_;
            ushort* op = (ushort*)out + (size_t)bb * P_ * C_ + cc;
#pragma unroll
            for (int i = 0; i < 4; ++i) {
                int rbase = mt * 64 + i * 16 + quad * 4;
                ushort4 rv = *(const ushort4*)&gr[rbase];
                float rf[4] = {bf2f(rv.x), bf2f(rv.y), bf2f(rv.z), bf2f(rv.w)};
#pragma unroll
                for (int rg = 0; rg < 4; ++rg) {
                    int row = rbase + rg;
                    float v = fmaxf(acc[i][j][rg] * gm[i * 4 + rg] + bt[i * 4 + rg], 0.f) + rf[rg];
                    op[(size_t)row * C_] = f2bf(v);
                }
            }
        }
    } else {
#pragma unroll
        for (int j = 0; j < 4; ++j) {
            int n = nt * 64 + j * 16 + ln;
            int bb = n >> 11;
            int pp = n & (P_ - 1);
            float* op = (float*)out + (size_t)bb * C_ * P_ + pp;
#pragma unroll
            for (int i = 0; i < 4; ++i)
#pragma unroll
                for (int rg = 0; rg < 4; ++rg) {
                    int row = mt * 64 + i * 16 + quad * 4 + rg;
                    op[(size_t)row * P_] =
                        fmaxf(acc[i][j][rg] * gm[i * 4 + rg] + bt[i * 4 + rg], 0.f);
                }
        }
    }
}

// out[b][d][hw] = pos ? r[b][d][pos-1] : x[b][d][hw]
__global__ __launch_bounds__(256) void output_kernel(const float* __restrict__ x,
                                                     const int* __restrict__ pos,
                                                     const float* __restrict__ r,
                                                     float* __restrict__ out) {
    size_t v = (size_t)blockIdx.x * 256 + threadIdx.x;
    size_t e0 = v * 4;
    int hw = (int)(e0 & (HW_ - 1));
    int bc = (int)(e0 >> 14);
    int d = bc & (C_ - 1);
    int b = bc >> 8;
    float4 xv = *(const float4*)&x[e0];
    int4 pv = *(const int4*)&pos[b * HW_ + hw];
    const float* rrow = r + ((size_t)b * C_ + d) * P_;
    float4 ov = xv;
    if (pv.x) ov.x = rrow[pv.x - 1];
    if (pv.y) ov.y = rrow[pv.y - 1];
    if (pv.z) ov.z = rrow[pv.z - 1];
    if (pv.w) ov.w = rrow[pv.w - 1];
    *(float4*)&out[e0] = ov;
}

extern "C" void kernel_launch(void* const* d_in, const int* in_sizes, int n_in,
                              void* d_out, int out_size, void* d_ws, size_t ws_size,
                              hipStream_t stream) {
    const float* x    = (const float*)d_in[0];
    const float* edge = (const float*)d_in[1];
    const float* Wadj = (const float*)d_in[2];
    const float* ga   = (const float*)d_in[3];
    const float* be   = (const float*)d_in[4];
    const float* Wg   = (const float*)d_in[5];
    const float* gw   = (const float*)d_in[6];
    const float* bw   = (const float*)d_in[7];
    float* out = (float*)d_out;

    char* ws = (char*)d_ws;
    int*                ncand = (int*)(ws + OFF_NCAND);
    unsigned long long* cand  = (unsigned long long*)(ws + OFF_CAND);
    int*                topk  = (int*)(ws + OFF_TOPK);
    int*                pos   = (int*)(ws + OFF_POS);
    int*                rankb = (int*)(ws + OFF_RANK);
    ushort*             gT    = (ushort*)(ws + OFF_GT);
    ushort*             z2    = (ushort*)(ws + OFF_Z2);
    ushort*             WadjB = (ushort*)(ws + OFF_WADJB);
    ushort*             WgB   = (ushort*)(ws + OFF_WGB);
    float*              rbuf  = (float*)(ws + OFF_R);

    prep_kernel<<<PREP_GRID, 256, 0, stream>>>(Wadj, WadjB, Wg, WgB, pos, rankb, ncand);
    compact_kernel<<<B_ * 64, 256, 0, stream>>>(edge, cand, ncand);
    {
        dim3 grid(64, 64, B_);
        rank_partial_kernel<<<grid, 256, 0, stream>>>(cand, ncand, rankb);
    }
    {
        dim3 grid(64, B_);
        rank_finalize_kernel<<<grid, 256, 0, stream>>>(cand, ncand, rankb, topk, pos, edge);
    }
    gather_lds_kernel<<<B_ * C_, 256, 0, stream>>>(x, topk, gT);

    // GEMM1: 64x128 LDS-tiled blocks -> 32x8 = 256 blocks x 4 waves
    gemm1_lds_kernel<<<256, 256, 0, stream>>>(WadjB, gT, ga, be, gT, z2);
    // GEMM2: M=256, N=8192 (b,p), K=256 -> 4x128 wave tiles = 512 waves
    gemm_wave_kernel<2, 256, 128, 1><<<512, 64, 0, stream>>>(WgB, z2, gw, bw, nullptr, rbuf);

    output_kernel<<<(B_ * C_ * HW_) / 4 / 256, 256, 0, stream>>>(x, pos, rbuf, out);
}

// Round 11
// 213.411 us; speedup vs baseline: 1.0593x; 1.0248x over previous
//
#include <hip/hip_runtime.h>
#include <stdint.h>

#define B_   4
#define C_   256
#define HW_  16384
#define P_   2048
#define THR_ 0.8f
#define INV_ 0.9999950000374997f

// ncand padded: counter b lives at ncand[b*16] (64 B apart -> no cacheline sharing)
#define NCIDX(b) ((b) << 4)

// ---------------- workspace layout (bytes) ----------------
#define OFF_NCAND 0
#define OFF_CAND  256                       // u64 cand[4][HW_]   512 KB
#define OFF_TOPK  524544                    // int topk[4][P_]     32 KB
#define OFF_POS   557312                    // int pos[4][HW_]    256 KB
#define OFF_G     819456                    // f32 r[4][C_][P_]     8 MB (GEMM2 out)
#define OFF_GT    9208064                   // bf16 gT[4][C_][P_]   4 MB  == [1024][2048]
#define OFF_Z2    13402368                  // bf16 z2[4][P_][C_]   4 MB  == [8192][256]
#define OFF_WADJB 17596672                  // bf16 Wadj[2048][2048] 8 MB
#define OFF_WGB   25985280                  // bf16 Wg[256][256]  128 KB
#define OFF_R     OFF_G
#define OFF_RANK  OFF_Z2                    // int rank[4][HW_] 256 KB, aliases z2 (dead before gemm1)

typedef __attribute__((ext_vector_type(8))) short bf16x8;
typedef __attribute__((ext_vector_type(4))) float f32x4;

__device__ __forceinline__ ushort f2bf(float f) {
    union { float f; unsigned u; } a; a.f = f;
    unsigned r = (a.u + 0x7fffu + ((a.u >> 16) & 1u)) >> 16;   // RNE
    return (ushort)r;
}
__device__ __forceinline__ float bf2f(ushort u) {
    union { unsigned u; float f; } a; a.u = (unsigned)u << 16;
    return a.f;
}

// Fused prep: convert Wadj (4096 blocks) + convert Wg (64 blocks) + zero pos/rank/ncand (128 blocks)
#define PREP_WADJ_BLOCKS 4096               // P_*P_/4/256
#define PREP_WG_BLOCKS   64                 // C_*C_/4/256
#define PREP_ZERO_BLOCKS 128                // (B_*HW_/4)*2 / 256
#define PREP_GRID (PREP_WADJ_BLOCKS + PREP_WG_BLOCKS + PREP_ZERO_BLOCKS)

__global__ __launch_bounds__(256) void prep_kernel(const float* __restrict__ Wadj,
                                                   ushort* __restrict__ WadjB,
                                                   const float* __restrict__ Wg,
                                                   ushort* __restrict__ WgB,
                                                   int* __restrict__ pos,
                                                   int* __restrict__ rankbuf,
                                                   int* __restrict__ ncand) {
    int bid = blockIdx.x;
    if (bid < PREP_WADJ_BLOCKS) {
        int i = bid * 256 + threadIdx.x;
        float4 v = ((const float4*)Wadj)[i];
        ushort4 o; o.x = f2bf(v.x); o.y = f2bf(v.y); o.z = f2bf(v.z); o.w = f2bf(v.w);
        ((ushort4*)WadjB)[i] = o;
    } else if (bid < PREP_WADJ_BLOCKS + PREP_WG_BLOCKS) {
        int i = (bid - PREP_WADJ_BLOCKS) * 256 + threadIdx.x;
        float4 v = ((const float4*)Wg)[i];
        ushort4 o; o.x = f2bf(v.x); o.y = f2bf(v.y); o.z = f2bf(v.z); o.w = f2bf(v.w);
        ((ushort4*)WgB)[i] = o;
    } else {
        int zb = bid - PREP_WADJ_BLOCKS - PREP_WG_BLOCKS;
        int i = zb * 256 + threadIdx.x;                // 0 .. 32767 (int4 units)
        int4 z = {0, 0, 0, 0};
        if (i < B_ * HW_ / 4) ((int4*)pos)[i] = z;
        else                  ((int4*)rankbuf)[i - B_ * HW_ / 4] = z;
        if (zb == 0 && threadIdx.x < 64) ncand[threadIdx.x] = 0;   // covers all padded slots
    }
}

// Block-aggregated compact: ballot+popcount per wave, LDS prefix across 4 waves,
// ONE global atomicAdd per block (256 total, padded counters). R6: -11.5us.
__global__ __launch_bounds__(256) void compact_kernel(const float* __restrict__ edge,
                                                      unsigned long long* __restrict__ cand,
                                                      int* __restrict__ ncand) {
    int b = blockIdx.x >> 6;
    int i = (blockIdx.x & 63) * 256 + threadIdx.x;
    float e = edge[b * HW_ + i];
    bool act = (e >= THR_);
    unsigned long long mask = __ballot(act);
    int lane = threadIdx.x & 63;
    int wid  = threadIdx.x >> 6;
    int before = __popcll(mask & ((1ull << lane) - 1ull));
    __shared__ int wcnt[4];
    __shared__ int base;
    if (lane == 0) wcnt[wid] = __popcll(mask);
    __syncthreads();
    if (threadIdx.x == 0) {
        int c0 = wcnt[0], c1 = wcnt[1], c2 = wcnt[2], c3 = wcnt[3];
        wcnt[0] = 0; wcnt[1] = c0; wcnt[2] = c0 + c1; wcnt[3] = c0 + c1 + c2;
        base = atomicAdd(&ncand[NCIDX(b)], c0 + c1 + c2 + c3);
    }
    __syncthreads();
    if (act) {
        int slot = base + wcnt[wid] + before;
        unsigned vb = __float_as_uint(e);
        cand[(size_t)b * HW_ + slot] =
            ((unsigned long long)vb << 32) | (unsigned long long)(0xFFFFFFFFu - (unsigned)i);
    }
}

// 2-D partial rank: block (jb, tb, b) counts, for each candidate j in jb-tile,
// how many candidates in tb-tile compare greater. atomicAdd into rankbuf[j].
// NOTE R4 lesson: super-tiling regressed; empty-block dispatch is nearly free.
__global__ __launch_bounds__(256) void rank_partial_kernel(
        const unsigned long long* __restrict__ cand,
        const int* __restrict__ ncand,
        int* __restrict__ rankbuf) {
    int b = blockIdx.z;
    int n = ncand[NCIDX(b)];
    int jb = blockIdx.x * 256, tb = blockIdx.y * 256;
    if (jb >= n || tb >= n) return;
    const unsigned long long* cb = cand + (size_t)b * HW_;
    __shared__ unsigned long long tile[256];
    int j = jb + threadIdx.x;
    unsigned long long kj = (j < n) ? cb[j] : 0ull;
    tile[threadIdx.x] = (tb + (int)threadIdx.x < n) ? cb[tb + threadIdx.x] : 0ull;
    __syncthreads();
    int cnt = 0;
#pragma unroll 16
    for (int k = 0; k < 256; ++k) cnt += (tile[k] > kj) ? 1 : 0;   // padded zeros never count
    if (j < n && cnt) atomicAdd(&rankbuf[b * HW_ + j], cnt);
}

// rank < P -> topk[rank]=idx, pos[idx]=rank+1.  Fallback (n < P) folded in.
__global__ __launch_bounds__(256) void rank_finalize_kernel(
        const unsigned long long* __restrict__ cand,
        const int* __restrict__ ncand,
        const int* __restrict__ rankbuf,
        int* __restrict__ topk,
        int* __restrict__ pos,
        const float* __restrict__ edge) {
    int b = blockIdx.y;
    int n = ncand[NCIDX(b)];
    int j = blockIdx.x * 256 + threadIdx.x;
    if (j < n) {
        int rank = rankbuf[b * HW_ + j];
        if (rank < P_) {
            int idx = (int)(0xFFFFFFFFu - (unsigned)(cand[(size_t)b * HW_ + j] & 0xFFFFFFFFull));
            topk[b * P_ + rank] = idx;
            pos[b * HW_ + idx] = rank + 1;
        }
    }
    if (n < P_ && blockIdx.x == 0 && threadIdx.x == 0) {
        int cnt = n;
        for (int i = 0; i < HW_ && cnt < P_; ++i) {
            if (edge[b * HW_ + i] < THR_) {
                topk[b * P_ + cnt] = i;
                pos[b * HW_ + i] = cnt + 1;
                cnt++;
            }
        }
    }
}

// index-driven gather: one block per (b,c) row; stage x-row in LDS (coalesced),
// gather topk positions from LDS, write gT row fully coalesced (16B/thread runs).
__global__ __launch_bounds__(256) void gather_lds_kernel(const float* __restrict__ x,
                                                         const int* __restrict__ topk,
                                                         ushort* __restrict__ gT) {
    __shared__ float row[HW_];              // 64 KB -> 2 blocks/CU
    int bc = blockIdx.x;                    // b*C_ + c
    int b = bc >> 8;
    const float* xr = x + (size_t)bc * HW_;
#pragma unroll
    for (int i = 0; i < 16; ++i)
        ((float4*)row)[threadIdx.x + i * 256] = ((const float4*)xr)[threadIdx.x + i * 256];
    __syncthreads();
    const int* tk = topk + b * P_;
    int p0 = threadIdx.x * 8;
    int4 i0 = *(const int4*)&tk[p0];
    int4 i1 = *(const int4*)&tk[p0 + 4];
    ushort4 o0, o1;
    o0.x = f2bf(row[i0.x]); o0.y = f2bf(row[i0.y]); o0.z = f2bf(row[i0.z]); o0.w = f2bf(row[i0.w]);
    o1.x = f2bf(row[i1.x]); o1.y = f2bf(row[i1.y]); o1.z = f2bf(row[i1.z]); o1.w = f2bf(row[i1.w]);
    ushort* gp = gT + (size_t)bc * P_ + p0;
    *(ushort4*)gp = o0;
    *(ushort4*)(gp + 4) = o1;
}

#define MFMA16(AB, BB)                                                              \
    _Pragma("unroll")                                                               \
    for (int i = 0; i < 4; ++i)                                                     \
    _Pragma("unroll")                                                               \
        for (int j = 0; j < 4; ++j)                                                 \
            acc[i][j] = __builtin_amdgcn_mfma_f32_16x16x32_bf16(                    \
                __builtin_bit_cast(bf16x8, AB[i]),                                  \
                __builtin_bit_cast(bf16x8, BB[j]), acc[i][j], 0, 0, 0);

// ============ GEMM1 v4: 64x64 LDS-tiled 4-wave blocks, 2 blocks/CU (R11) ============
// R10 (v3, 64x128, 256 blocks = 1 block/CU) left gemm1 at ~33us: per K-iter the
// global-return + ds_write + barrier drain is exposed because nothing else is
// resident on the CU. v4 splits N 128->64: grid 32x16 = 512 blocks = 2/CU
// (LDS 36KB allows 4/CU), 2 waves/SIMD -> block B computes while block A drains.
// Per-wave 32x32 (acc[2][2], 8 MFMA + 8 ds_read_b128 per iter). Stride 72
// ushorts: b128 reads AND staging writes both hit the 8-words/bank minimum.
#define G1_LDK 72
__global__ __launch_bounds__(256) void gemm1_lds_kernel(
        const ushort* __restrict__ A, const ushort* __restrict__ B,
        const float* __restrict__ gamma, const float* __restrict__ beta,
        const ushort* __restrict__ residT, ushort* __restrict__ out) {
    __shared__ ushort Asm[2][64][G1_LDK];    // 18 KB
    __shared__ ushort Bsm[2][64][G1_LDK];    // 18 KB
    const int mtb = blockIdx.x >> 4;         // 0..31 (M tile of 64)
    const int ntb = blockIdx.x & 15;         // 0..15 (N tile of 64)
    const int w   = threadIdx.x >> 6;        // wave 0..3
    const int wr  = w >> 1, wc = w & 1;      // 2x2 -> per-wave 32x32
    const int lane = threadIdx.x & 63;
    const int quad = lane >> 4, ln = lane & 15;
    const int tid  = threadIdx.x;
    const int srow = tid >> 3;               // 0..31 (staging row base)
    const int sslot = tid & 7;               // 0..7  (16B granule in 128B row)

    // staging bases: granules (srow, srow+32) for both 64-row panels
    const ushort* gA = A + (size_t)(mtb * 64 + srow) * 2048 + sslot * 8;
    const ushort* gB = B + (size_t)(ntb * 64 + srow) * 2048 + sslot * 8;

    f32x4 acc[2][2];
#pragma unroll
    for (int i = 0; i < 2; ++i)
#pragma unroll
        for (int j = 0; j < 2; ++j) acc[i][j] = (f32x4){0.f, 0.f, 0.f, 0.f};

    uint4 ra[2], rb[2];
#pragma unroll
    for (int m = 0; m < 2; ++m) {
        ra[m] = *(const uint4*)(gA + (size_t)m * 32 * 2048);
        rb[m] = *(const uint4*)(gB + (size_t)m * 32 * 2048);
    }
#pragma unroll
    for (int m = 0; m < 2; ++m) {
        *(uint4*)&Asm[0][srow + m * 32][sslot * 8] = ra[m];
        *(uint4*)&Bsm[0][srow + m * 32][sslot * 8] = rb[m];
    }
    __syncthreads();

    for (int t = 0; t < 32; ++t) {
        const int cur = t & 1;
        if (t < 31) {
            const int ko = (t + 1) * 64;
#pragma unroll
            for (int m = 0; m < 2; ++m) {
                ra[m] = *(const uint4*)(gA + (size_t)m * 32 * 2048 + ko);
                rb[m] = *(const uint4*)(gB + (size_t)m * 32 * 2048 + ko);
            }
        }
#pragma unroll
        for (int kk = 0; kk < 2; ++kk) {
            uint4 av[2], bv[2];
#pragma unroll
            for (int i = 0; i < 2; ++i) {
                av[i] = *(const uint4*)&Asm[cur][wr * 32 + i * 16 + ln][kk * 32 + quad * 8];
                bv[i] = *(const uint4*)&Bsm[cur][wc * 32 + i * 16 + ln][kk * 32 + quad * 8];
            }
#pragma unroll
            for (int i = 0; i < 2; ++i)
#pragma unroll
                for (int j = 0; j < 2; ++j)
                    acc[i][j] = __builtin_amdgcn_mfma_f32_16x16x32_bf16(
                        __builtin_bit_cast(bf16x8, av[i]),
                        __builtin_bit_cast(bf16x8, bv[j]), acc[i][j], 0, 0, 0);
        }
        if (t < 31) {
#pragma unroll
            for (int m = 0; m < 2; ++m) {
                *(uint4*)&Asm[cur ^ 1][srow + m * 32][sslot * 8] = ra[m];
                *(uint4*)&Bsm[cur ^ 1][srow + m * 32][sslot * 8] = rb[m];
            }
        }
        __syncthreads();
    }

    float gm[8], bt[8];
#pragma unroll
    for (int i = 0; i < 2; ++i)
#pragma unroll
        for (int rg = 0; rg < 4; ++rg) {
            int row = mtb * 64 + wr * 32 + i * 16 + quad * 4 + rg;
            gm[i * 4 + rg] = gamma[row] * INV_;
            bt[i * 4 + rg] = beta[row];
        }
#pragma unroll
    for (int j = 0; j < 2; ++j) {
        int n = ntb * 64 + wc * 32 + j * 16 + ln;
        int bb = n >> 8;
        int cc = n & (C_ - 1);
        const ushort* gr = residT + (size_t)n * P_;           // gT row (b,c), indexed by o
        ushort* op = out + (size_t)bb * P_ * C_ + cc;
#pragma unroll
        for (int i = 0; i < 2; ++i) {
            int rbase = mtb * 64 + wr * 32 + i * 16 + quad * 4;
            ushort4 rv = *(const ushort4*)&gr[rbase];
            float rf[4] = {bf2f(rv.x), bf2f(rv.y), bf2f(rv.z), bf2f(rv.w)};
#pragma unroll
            for (int rg = 0; rg < 4; ++rg) {
                float v = fmaxf(acc[i][j][rg] * gm[i * 4 + rg] + bt[i * 4 + rg], 0.f) + rf[rg];
                op[(size_t)(rbase + rg) * C_] = f2bf(v);
            }
        }
    }
}

// ------------- per-wave NT MFMA GEMM (gemm2 only), 4-deep ring -------------
// MODE 2 (gemm2): M=256 (d), N=8192 (b*2048+p), K=256
template<int MODE, int KDIM, int NTN, int WPB>
__global__ __launch_bounds__(64 * WPB) void gemm_wave_kernel(
        const ushort* __restrict__ A, const ushort* __restrict__ B,
        const float* __restrict__ gamma, const float* __restrict__ beta,
        const ushort* __restrict__ residT, void* __restrict__ out) {
    constexpr int KSTEPS = KDIM / 32;        // 32-k chunks; KSTEPS is a multiple of 4
    const int bid = blockIdx.x;
    const int wid = threadIdx.x >> 6;
    const int mt = (bid / NTN) * WPB + wid;
    const int nt = bid % NTN;
    const int lane = threadIdx.x & 63;
    const int quad = lane >> 4, ln = lane & 15;

    const ushort* pa[4];
    const ushort* pb[4];
#pragma unroll
    for (int i = 0; i < 4; ++i) {
        pa[i] = A + (size_t)(mt * 64 + i * 16 + ln) * KDIM + quad * 8;
        pb[i] = B + (size_t)(nt * 64 + i * 16 + ln) * KDIM + quad * 8;
    }

    f32x4 acc[4][4];
#pragma unroll
    for (int i = 0; i < 4; ++i)
#pragma unroll
        for (int j = 0; j < 4; ++j) acc[i][j] = (f32x4){0.f, 0.f, 0.f, 0.f};

    uint4 A4[4][4], B4[4][4];
#pragma unroll
    for (int t = 0; t < 4; ++t)
#pragma unroll
        for (int i = 0; i < 4; ++i) {
            A4[t][i] = *(const uint4*)(pa[i] + t * 32);
            B4[t][i] = *(const uint4*)(pb[i] + t * 32);
        }

    int koff = 4 * 32;
    for (int s = 0; s < KSTEPS - 4; s += 4) {
#pragma unroll
        for (int t = 0; t < 4; ++t) {
            MFMA16(A4[t], B4[t])
#pragma unroll
            for (int i = 0; i < 4; ++i) {
                A4[t][i] = *(const uint4*)(pa[i] + koff + t * 32);
                B4[t][i] = *(const uint4*)(pb[i] + koff + t * 32);
            }
        }
        koff += 128;
    }
#pragma unroll
    for (int t = 0; t < 4; ++t) {
        MFMA16(A4[t], B4[t])
    }

    float gm[16], bt[16];
#pragma unroll
    for (int i = 0; i < 4; ++i)
#pragma unroll
        for (int rg = 0; rg < 4; ++rg) {
            int row = mt * 64 + i * 16 + quad * 4 + rg;
            gm[i * 4 + rg] = gamma[row] * INV_;
            bt[i * 4 + rg] = beta[row];
        }

    if (MODE == 1) {
#pragma unroll
        for (int j = 0; j < 4; ++j) {
            int n = nt * 64 + j * 16 + ln;
            int bb = n >> 8;
            int cc = n & (C_ - 1);
            const ushort* gr = residT + (size_t)n * P_;
            ushort* op = (ushort*)out + (size_t)bb * P_ * C_ + cc;
#pragma unroll
            for (int i = 0; i < 4; ++i) {
                int rbase = mt * 64 + i * 16 + quad * 4;
                ushort4 rv = *(const ushort4*)&gr[rbase];
                float rf[4] = {bf2f(rv.x), bf2f(rv.y), bf2f(rv.z), bf2f(rv.w)};
#pragma unroll
                for (int rg = 0; rg < 4; ++rg) {
                    int row = rbase + rg;
                    float v = fmaxf(acc[i][j][rg] * gm[i * 4 + rg] + bt[i * 4 + rg], 0.f) + rf[rg];
                    op[(size_t)row * C_] = f2bf(v);
                }
            }
        }
    } else {
#pragma unroll
        for (int j = 0; j < 4; ++j) {
            int n = nt * 64 + j * 16 + ln;
            int bb = n >> 11;
            int pp = n & (P_ - 1);
            float* op = (float*)out + (size_t)bb * C_ * P_ + pp;
#pragma unroll
            for (int i = 0; i < 4; ++i)
#pragma unroll
                for (int rg = 0; rg < 4; ++rg) {
                    int row = mt * 64 + i * 16 + quad * 4 + rg;
                    op[(size_t)row * P_] =
                        fmaxf(acc[i][j][rg] * gm[i * 4 + rg] + bt[i * 4 + rg], 0.f);
                }
        }
    }
}

// out[b][d][hw] = pos ? r[b][d][pos-1] : x[b][d][hw]
__global__ __launch_bounds__(256) void output_kernel(const float* __restrict__ x,
                                                     const int* __restrict__ pos,
                                                     const float* __restrict__ r,
                                                     float* __restrict__ out) {
    size_t v = (size_t)blockIdx.x * 256 + threadIdx.x;
    size_t e0 = v * 4;
    int hw = (int)(e0 & (HW_ - 1));
    int bc = (int)(e0 >> 14);
    int d = bc & (C_ - 1);
    int b = bc >> 8;
    float4 xv = *(const float4*)&x[e0];
    int4 pv = *(const int4*)&pos[b * HW_ + hw];
    const float* rrow = r + ((size_t)b * C_ + d) * P_;
    float4 ov = xv;
    if (pv.x) ov.x = rrow[pv.x - 1];
    if (pv.y) ov.y = rrow[pv.y - 1];
    if (pv.z) ov.z = rrow[pv.z - 1];
    if (pv.w) ov.w = rrow[pv.w - 1];
    *(float4*)&out[e0] = ov;
}

extern "C" void kernel_launch(void* const* d_in, const int* in_sizes, int n_in,
                              void* d_out, int out_size, void* d_ws, size_t ws_size,
                              hipStream_t stream) {
    const float* x    = (const float*)d_in[0];
    const float* edge = (const float*)d_in[1];
    const float* Wadj = (const float*)d_in[2];
    const float* ga   = (const float*)d_in[3];
    const float* be   = (const float*)d_in[4];
    const float* Wg   = (const float*)d_in[5];
    const float* gw   = (const float*)d_in[6];
    const float* bw   = (const float*)d_in[7];
    float* out = (float*)d_out;

    char* ws = (char*)d_ws;
    int*                ncand = (int*)(ws + OFF_NCAND);
    unsigned long long* cand  = (unsigned long long*)(ws + OFF_CAND);
    int*                topk  = (int*)(ws + OFF_TOPK);
    int*                pos   = (int*)(ws + OFF_POS);
    int*                rankb = (int*)(ws + OFF_RANK);
    ushort*             gT    = (ushort*)(ws + OFF_GT);
    ushort*             z2    = (ushort*)(ws + OFF_Z2);
    ushort*             WadjB = (ushort*)(ws + OFF_WADJB);
    ushort*             WgB   = (ushort*)(ws + OFF_WGB);
    float*              rbuf  = (float*)(ws + OFF_R);

    prep_kernel<<<PREP_GRID, 256, 0, stream>>>(Wadj, WadjB, Wg, WgB, pos, rankb, ncand);
    compact_kernel<<<B_ * 64, 256, 0, stream>>>(edge, cand, ncand);
    {
        dim3 grid(64, 64, B_);
        rank_partial_kernel<<<grid, 256, 0, stream>>>(cand, ncand, rankb);
    }
    {
        dim3 grid(64, B_);
        rank_finalize_kernel<<<grid, 256, 0, stream>>>(cand, ncand, rankb, topk, pos, edge);
    }
    gather_lds_kernel<<<B_ * C_, 256, 0, stream>>>(x, topk, gT);

    // GEMM1: 64x64 LDS-tiled blocks -> 32x16 = 512 blocks x 4 waves (2 blocks/CU)
    gemm1_lds_kernel<<<512, 256, 0, stream>>>(WadjB, gT, ga, be, gT, z2);
    // GEMM2: M=256, N=8192 (b,p), K=256 -> 4x128 wave tiles = 512 waves
    gemm_wave_kernel<2, 256, 128, 1><<<512, 64, 0, stream>>>(WgB, z2, gw, bw, nullptr, rbuf);

    output_kernel<<<(B_ * C_ * HW_) / 4 / 256, 256, 0, stream>>>(x, pos, rbuf, out);
}